// Round 4
// baseline (736.437 us; speedup 1.0000x reference)
//
#include <hip/hip_runtime.h>

// VQ-VAE vector quantizer, MI355X — bitwise emulation of the numpy f32 reference.
// z: (4,256,16,32,32) f32 ; emb: (1024,256) f32
// out (f32, concatenated): z_q_st[16777216] | vq_loss | perplexity | indices[65536]
//
// Exactness contract (validated rounds 2-3, absmax 0):
//   x_sq[n], e_sq[k]: numpy pairwise sum of fl32(v*v) (two 128-blocks, 8 accumulators)
//   xe[n][k]: single sequential f32 FMA chain over c = 0..255 (BLAS sgemm order)
//   d = fl32( fl32(x_sq + e_sq) - 2*xe ), argmin with first-min tie-break.
//
// Round-4: argmin was latency-stalled at 2 waves/SIMD (grid 512 = 2 blocks/CU,
// VALUBusy 55%). Now 512-thread blocks (8 waves), 8n x 4k per thread ->
// 4 waves/SIMD at the same FMA count. Gather: idx hoisted, float4 z/out,
// embT-row gathers (L1-resident 4 KB row per c).

#define C_DIM 256
#define K_CODES 1024
#define N_VEC 65536
#define BN 128
#define BK 128
#define CB 64

#define OUT_ZQ_SIZE 16777216
#define OUT_LOSS_OFF 16777216
#define OUT_PP_OFF   16777217
#define OUT_IDX_OFF  16777218

// ws: [0,1048576) embT f32[256][1024] ; [1048576,1052672) esq f32[1024] ;
//     [1052672,1314816) xsq f32[65536] ; [1314816,1318912) counts u32[1024] ;
//     [1318912,1318920) loss f64

__global__ __launch_bounds__(256) void transpose_kernel(const float* __restrict__ emb,
                                                        float* __restrict__ embT) {
    __shared__ float t[64][65];
    const int k0 = blockIdx.x * 64;
    const int c0 = blockIdx.y * 64;
    const int tx = threadIdx.x & 63, ty = threadIdx.x >> 6;
    for (int r = ty; r < 64; r += 4)
        t[r][tx] = emb[(k0 + r) * C_DIM + c0 + tx];
    __syncthreads();
    for (int r = ty; r < 64; r += 4)
        embT[(c0 + r) * K_CODES + k0 + tx] = t[tx][r];
}

// numpy pairwise_sum of squares for a contiguous 128-block
__device__ __forceinline__ float pairwise_sq_128(const float* p) {
#pragma clang fp contract(off)
    float r[8];
#pragma unroll
    for (int j = 0; j < 8; ++j) { float v = p[j]; r[j] = v * v; }
#pragma unroll
    for (int i = 8; i < 128; i += 8)
#pragma unroll
        for (int j = 0; j < 8; ++j) { float v = p[i + j]; float t = v * v; r[j] = r[j] + t; }
    return ((r[0] + r[1]) + (r[2] + r[3])) + ((r[4] + r[5]) + (r[6] + r[7]));
}

__global__ __launch_bounds__(256) void esq_kernel(const float* __restrict__ emb,
                                                  float* __restrict__ esq) {
#pragma clang fp contract(off)
    __shared__ float tile[64 * 260];
    const int tid = threadIdx.x;
    const int k0 = blockIdx.x * 64;
#pragma unroll
    for (int r = 0; r < 64; ++r) {
        int idx = r * 256 + tid;
        tile[(idx >> 8) * 260 + (idx & 255)] = emb[k0 * C_DIM + idx];
    }
    __syncthreads();
    if (tid < 64) {
        const float* row = &tile[tid * 260];
        esq[k0 + tid] = pairwise_sq_128(row) + pairwise_sq_128(row + 128);
    }
}

__global__ __launch_bounds__(256) void xsq_kernel(const float* __restrict__ z,
                                                  float* __restrict__ xsq) {
#pragma clang fp contract(off)
    const int n = blockIdx.x * 256 + threadIdx.x;
    const int b = n >> 14, s = n & 16383;
    const float* base = z + ((size_t)b << 22) + s;
    float r[8], res;
#pragma unroll
    for (int j = 0; j < 8; ++j) { float v = base[(size_t)j << 14]; r[j] = v * v; }
#pragma unroll
    for (int i = 8; i < 128; i += 8)
#pragma unroll
        for (int j = 0; j < 8; ++j) { float v = base[(size_t)(i + j) << 14]; float t = v * v; r[j] = r[j] + t; }
    res = ((r[0] + r[1]) + (r[2] + r[3])) + ((r[4] + r[5]) + (r[6] + r[7]));
#pragma unroll
    for (int j = 0; j < 8; ++j) { float v = base[(size_t)(128 + j) << 14]; r[j] = v * v; }
#pragma unroll
    for (int i = 136; i < 256; i += 8)
#pragma unroll
        for (int j = 0; j < 8; ++j) { float v = base[(size_t)(i + j) << 14]; float t = v * v; r[j] = r[j] + t; }
    res = res + (((r[0] + r[1]) + (r[2] + r[3])) + ((r[4] + r[5]) + (r[6] + r[7])));
    xsq[n] = res;
}

__global__ __launch_bounds__(512, 4) void argmin_kernel(
    const float* __restrict__ z, const float* __restrict__ embT,
    const float* __restrict__ esq, const float* __restrict__ xsq,
    float* __restrict__ out_idx, unsigned* __restrict__ counts) {
#pragma clang fp contract(off)
    __shared__ float zs[CB * BN];   // [c][n], 32 KB

    const int tid = threadIdx.x;
    const int tn = tid >> 5;        // 0..15 -> n-octet
    const int tk = tid & 31;        // 0..31 -> k-quad
    const int n0 = blockIdx.x * BN;
    const int b  = n0 >> 14;
    const int s0 = n0 & 16383;
    const float* zb = z + ((size_t)b << 22) + s0;

    float xsl[8];
    {
        float4 a = *reinterpret_cast<const float4*>(&xsq[n0 + 8 * tn]);
        float4 c = *reinterpret_cast<const float4*>(&xsq[n0 + 8 * tn + 4]);
        xsl[0] = a.x; xsl[1] = a.y; xsl[2] = a.z; xsl[3] = a.w;
        xsl[4] = c.x; xsl[5] = c.y; xsl[6] = c.z; xsl[7] = c.w;
    }

    float minv[8];
    int   mini[8];
#pragma unroll
    for (int i = 0; i < 8; ++i) { minv[i] = 3.4e38f; mini[i] = 0; }

    for (int kt = 0; kt < K_CODES / BK; ++kt) {
        const int k0 = kt * BK;
        float esql[4];
        {
            float4 a = *reinterpret_cast<const float4*>(&esq[k0 + 4 * tk]);
            esql[0] = a.x; esql[1] = a.y; esql[2] = a.z; esql[3] = a.w;
        }

        float acc[8][4];
#pragma unroll
        for (int i = 0; i < 8; ++i)
#pragma unroll
            for (int j = 0; j < 4; ++j) acc[i][j] = 0.0f;

        for (int cc = 0; cc < C_DIM / CB; ++cc) {
            const int c0 = cc * CB;
            __syncthreads();   // previous chunk fully consumed
            // stage zs[c][n] chunk: 2048 float4, 4 per thread, coalesced
#pragma unroll
            for (int r = 0; r < 4; ++r) {
                int lin  = r * 512 + tid;       // float4 id
                int cl   = lin >> 5;            // 0..63
                int u    = lin & 31;            // float4 within row of 128
                float4 v = *reinterpret_cast<const float4*>(
                    zb + ((size_t)(c0 + cl) << 14) + u * 4);
                *reinterpret_cast<float4*>(&zs[cl * BN + u * 4]) = v;
            }
            __syncthreads();

            const float* ecol = embT + (size_t)c0 * K_CODES + k0 + 4 * tk;
#pragma unroll 4
            for (int c = 0; c < CB; ++c) {
                float4 z0 = *reinterpret_cast<const float4*>(&zs[c * BN + 8 * tn]);
                float4 z1 = *reinterpret_cast<const float4*>(&zs[c * BN + 8 * tn + 4]);
                float4 ev = *reinterpret_cast<const float4*>(ecol + (size_t)c * K_CODES);
                float zr[8] = {z0.x, z0.y, z0.z, z0.w, z1.x, z1.y, z1.z, z1.w};
                float er[4] = {ev.x, ev.y, ev.z, ev.w};
#pragma unroll
                for (int i = 0; i < 8; ++i)
#pragma unroll
                    for (int j = 0; j < 4; ++j)
                        acc[i][j] = fmaf(zr[i], er[j], acc[i][j]);
            }
        }

        // distances + running first-min (kg strictly ascending per thread)
#pragma unroll
        for (int j = 0; j < 4; ++j) {
            int kg = k0 + 4 * tk + j;
#pragma unroll
            for (int i = 0; i < 8; ++i) {
                float t1 = xsl[i] + esql[j];
                float r  = t1 - 2.0f * acc[i][j];
                if (r < minv[i]) { minv[i] = r; mini[i] = kg; }
            }
        }
    }

    // reduce across the 32 tk lanes sharing each tn (32 consecutive lanes)
#pragma unroll
    for (int i = 0; i < 8; ++i) {
        for (int off = 16; off >= 1; off >>= 1) {
            float ov = __shfl_xor(minv[i], off, 64);
            int   oi = __shfl_xor(mini[i], off, 64);
            if (ov < minv[i] || (ov == minv[i] && oi < mini[i])) { minv[i] = ov; mini[i] = oi; }
        }
    }
    if (tk == 0) {
#pragma unroll
        for (int i = 0; i < 8; ++i) {
            int n = n0 + 8 * tn + i;
            out_idx[n] = (float)mini[i];
            atomicAdd(&counts[mini[i]], 1u);
        }
    }
}

// block: fixed b, 1024-s range, 64-c range. idx hoisted per thread (4 s each),
// z/out float4, emb gathered from embT row (4 KB, L1-resident per c).
__global__ __launch_bounds__(256) void gather_kernel(
    const float* __restrict__ z, const float* __restrict__ embT,
    const float* __restrict__ out_idx, float* __restrict__ out,
    double* __restrict__ loss_acc) {
    const int tid = threadIdx.x;
    const int ct = blockIdx.x & 3;          // c-tile (64 c)
    const int st = (blockIdx.x >> 2) & 15;  // s-tile (1024 s)
    const int b  = blockIdx.x >> 6;         // batch
    const int s0 = st * 1024;
    const int c0 = ct * 64;

    int idx[4];
#pragma unroll
    for (int q = 0; q < 4; ++q)
        idx[q] = (int)out_idx[(b << 14) + s0 + 4 * tid + q];

    const float* zb = z + ((size_t)b << 22) + s0 + 4 * tid;
    float* ob = out + ((size_t)b << 22) + s0 + 4 * tid;

    double local = 0.0;
    for (int c = 0; c < 64; ++c) {
        const int cg = c0 + c;
        const float* er = embT + (size_t)cg * K_CODES;
        float4 zv = *reinterpret_cast<const float4*>(zb + ((size_t)cg << 14));
        float4 ov;
        float d0 = er[idx[0]] - zv.x;
        float d1 = er[idx[1]] - zv.y;
        float d2 = er[idx[2]] - zv.z;
        float d3 = er[idx[3]] - zv.w;
        ov.x = zv.x + d0; ov.y = zv.y + d1; ov.z = zv.z + d2; ov.w = zv.w + d3;
        *reinterpret_cast<float4*>(ob + ((size_t)cg << 14)) = ov;
        local += (double)d0 * d0 + (double)d1 * d1 + (double)d2 * d2 + (double)d3 * d3;
    }
    for (int off = 32; off >= 1; off >>= 1) local += __shfl_down(local, off, 64);
    __shared__ double red[4];
    if ((tid & 63) == 0) red[tid >> 6] = local;
    __syncthreads();
    if (tid == 0) {
        double s = red[0] + red[1] + red[2] + red[3];
        atomicAdd(loss_acc, s);
    }
}

__global__ void finalize_kernel(const unsigned* __restrict__ counts,
                                const double* __restrict__ loss_acc,
                                float* __restrict__ out) {
    int tid = threadIdx.x;
    double s = 0.0;
    for (int k = tid; k < K_CODES; k += 256) {
        float avg = (float)counts[k] / 65536.0f;
        float t = avg * logf(avg + 1e-10f);
        s += (double)t;
    }
    for (int off = 32; off >= 1; off >>= 1) s += __shfl_down(s, off, 64);
    __shared__ double red[4];
    if ((tid & 63) == 0) red[tid >> 6] = s;
    __syncthreads();
    if (tid == 0) {
        double tot = red[0] + red[1] + red[2] + red[3];
        out[OUT_PP_OFF]   = expf((float)(-tot));
        out[OUT_LOSS_OFF] = 1.25f * (float)(loss_acc[0] / 16777216.0);
    }
}

extern "C" void kernel_launch(void* const* d_in, const int* in_sizes, int n_in,
                              void* d_out, int out_size, void* d_ws, size_t ws_size,
                              hipStream_t stream) {
    const float* z   = (const float*)d_in[0];
    const float* emb = (const float*)d_in[1];
    float* out = (float*)d_out;

    float*    embT     = (float*)d_ws;
    float*    esq      = (float*)((char*)d_ws + 1048576);
    float*    xsq      = (float*)((char*)d_ws + 1052672);
    unsigned* counts   = (unsigned*)((char*)d_ws + 1314816);
    double*   loss_acc = (double*)((char*)d_ws + 1318912);
    float*    out_idx  = out + OUT_IDX_OFF;

    hipMemsetAsync((char*)d_ws + 1314816, 0, 4104, stream);   // counts + loss
    transpose_kernel<<<dim3(16, 4), 256, 0, stream>>>(emb, embT);
    esq_kernel<<<K_CODES / 64, 256, 0, stream>>>(emb, esq);
    xsq_kernel<<<N_VEC / 256, 256, 0, stream>>>(z, xsq);
    argmin_kernel<<<N_VEC / BN, 512, 0, stream>>>(z, embT, esq, xsq, out_idx, counts);
    gather_kernel<<<256, 256, 0, stream>>>(z, embT, out_idx, out, loss_acc);
    finalize_kernel<<<1, 256, 0, stream>>>(counts, loss_acc, out);
}

// Round 5
// 571.349 us; speedup vs baseline: 1.2889x; 1.2889x over previous
//
#include <hip/hip_runtime.h>

// VQ-VAE vector quantizer, MI355X — bitwise emulation of the numpy f32 reference.
// z: (4,256,16,32,32) f32 ; emb: (1024,256) f32
// out (f32, concatenated): z_q_st[16777216] | vq_loss | perplexity | indices[65536]
//
// Exactness contract (validated rounds 2-4, absmax 0):
//   x_sq[n], e_sq[k]: numpy pairwise sum of fl32(v*v) (two 128-blocks, 8 accumulators)
//   xe[n][k]: single sequential f32 FMA chain over c = 0..255 (BLAS sgemm order)
//   d = fl32( fl32(x_sq + e_sq) - 2*xe ), argmin with first-min tie-break.
//
// Round-5: round 4 went LDS-pipe-bound (8nx4k tile halved z-reuse: 384 LDS cyc
// vs 256 VALU cyc per CU per c-step). Restore 8nx8k (64 FMA / 2 ds_read_b128)
// and get 4 waves/SIMD via MORE BLOCKS instead: BN=64, BK=256, grid 1024
// (4 blocks/CU, 16 KB LDS each). k-octet split as two coalesced 128-halves.

#define C_DIM 256
#define K_CODES 1024
#define N_VEC 65536
#define BN 64
#define BK 256
#define CB 64

#define OUT_ZQ_SIZE 16777216
#define OUT_LOSS_OFF 16777216
#define OUT_PP_OFF   16777217
#define OUT_IDX_OFF  16777218

// ws: [0,1048576) embT f32[256][1024] ; [1048576,1052672) esq f32[1024] ;
//     [1052672,1314816) xsq f32[65536] ; [1314816,1318912) counts u32[1024] ;
//     [1318912,1318920) loss f64

__global__ __launch_bounds__(256) void transpose_kernel(const float* __restrict__ emb,
                                                        float* __restrict__ embT) {
    __shared__ float t[64][65];
    const int k0 = blockIdx.x * 64;
    const int c0 = blockIdx.y * 64;
    const int tx = threadIdx.x & 63, ty = threadIdx.x >> 6;
    for (int r = ty; r < 64; r += 4)
        t[r][tx] = emb[(k0 + r) * C_DIM + c0 + tx];
    __syncthreads();
    for (int r = ty; r < 64; r += 4)
        embT[(c0 + r) * K_CODES + k0 + tx] = t[tx][r];
}

// numpy pairwise_sum of squares for a contiguous 128-block
__device__ __forceinline__ float pairwise_sq_128(const float* p) {
#pragma clang fp contract(off)
    float r[8];
#pragma unroll
    for (int j = 0; j < 8; ++j) { float v = p[j]; r[j] = v * v; }
#pragma unroll
    for (int i = 8; i < 128; i += 8)
#pragma unroll
        for (int j = 0; j < 8; ++j) { float v = p[i + j]; float t = v * v; r[j] = r[j] + t; }
    return ((r[0] + r[1]) + (r[2] + r[3])) + ((r[4] + r[5]) + (r[6] + r[7]));
}

__global__ __launch_bounds__(256) void esq_kernel(const float* __restrict__ emb,
                                                  float* __restrict__ esq) {
#pragma clang fp contract(off)
    __shared__ float tile[64 * 260];
    const int tid = threadIdx.x;
    const int k0 = blockIdx.x * 64;
#pragma unroll
    for (int r = 0; r < 64; ++r) {
        int idx = r * 256 + tid;
        tile[(idx >> 8) * 260 + (idx & 255)] = emb[k0 * C_DIM + idx];
    }
    __syncthreads();
    if (tid < 64) {
        const float* row = &tile[tid * 260];
        esq[k0 + tid] = pairwise_sq_128(row) + pairwise_sq_128(row + 128);
    }
}

__global__ __launch_bounds__(256) void xsq_kernel(const float* __restrict__ z,
                                                  float* __restrict__ xsq) {
#pragma clang fp contract(off)
    const int n = blockIdx.x * 256 + threadIdx.x;
    const int b = n >> 14, s = n & 16383;
    const float* base = z + ((size_t)b << 22) + s;
    float r[8], res;
#pragma unroll
    for (int j = 0; j < 8; ++j) { float v = base[(size_t)j << 14]; r[j] = v * v; }
#pragma unroll
    for (int i = 8; i < 128; i += 8)
#pragma unroll
        for (int j = 0; j < 8; ++j) { float v = base[(size_t)(i + j) << 14]; float t = v * v; r[j] = r[j] + t; }
    res = ((r[0] + r[1]) + (r[2] + r[3])) + ((r[4] + r[5]) + (r[6] + r[7]));
#pragma unroll
    for (int j = 0; j < 8; ++j) { float v = base[(size_t)(128 + j) << 14]; r[j] = v * v; }
#pragma unroll
    for (int i = 136; i < 256; i += 8)
#pragma unroll
        for (int j = 0; j < 8; ++j) { float v = base[(size_t)(i + j) << 14]; float t = v * v; r[j] = r[j] + t; }
    res = res + (((r[0] + r[1]) + (r[2] + r[3])) + ((r[4] + r[5]) + (r[6] + r[7])));
    xsq[n] = res;
}

__global__ __launch_bounds__(256, 4) void argmin_kernel(
    const float* __restrict__ z, const float* __restrict__ embT,
    const float* __restrict__ esq, const float* __restrict__ xsq,
    float* __restrict__ out_idx, unsigned* __restrict__ counts) {
#pragma clang fp contract(off)
    __shared__ float zs[CB * BN];   // [c][n], 16 KB

    const int tid = threadIdx.x;
    const int tn = tid >> 5;        // 0..7  -> n-octet
    const int tk = tid & 31;        // 0..31 -> k-quad (two 128-halves)
    const int n0 = blockIdx.x * BN;
    const int b  = n0 >> 14;
    const int s0 = n0 & 16383;
    const float* zb = z + ((size_t)b << 22) + s0;

    float xsl[8];
    {
        float4 a = *reinterpret_cast<const float4*>(&xsq[n0 + 8 * tn]);
        float4 c = *reinterpret_cast<const float4*>(&xsq[n0 + 8 * tn + 4]);
        xsl[0] = a.x; xsl[1] = a.y; xsl[2] = a.z; xsl[3] = a.w;
        xsl[4] = c.x; xsl[5] = c.y; xsl[6] = c.z; xsl[7] = c.w;
    }

    float minv[8];
    int   mini[8];
#pragma unroll
    for (int i = 0; i < 8; ++i) { minv[i] = 3.4e38f; mini[i] = 0; }

    for (int kt = 0; kt < K_CODES / BK; ++kt) {
        const int k0 = kt * BK;
        // k handled by this thread: k0+4*tk+j (j 0..3) and k0+128+4*tk+j
        float esql[8];
        {
            float4 a = *reinterpret_cast<const float4*>(&esq[k0 + 4 * tk]);
            float4 c = *reinterpret_cast<const float4*>(&esq[k0 + 128 + 4 * tk]);
            esql[0] = a.x; esql[1] = a.y; esql[2] = a.z; esql[3] = a.w;
            esql[4] = c.x; esql[5] = c.y; esql[6] = c.z; esql[7] = c.w;
        }

        float acc[8][8];
#pragma unroll
        for (int i = 0; i < 8; ++i)
#pragma unroll
            for (int j = 0; j < 8; ++j) acc[i][j] = 0.0f;

        for (int cc = 0; cc < C_DIM / CB; ++cc) {
            const int c0 = cc * CB;
            __syncthreads();   // previous chunk fully consumed
            // stage zs[c][n]: 1024 float4, 4 per thread, coalesced (256 B / 16 lanes)
#pragma unroll
            for (int r = 0; r < 4; ++r) {
                int lin  = r * 256 + tid;       // float4 id
                int cl   = lin >> 4;            // 0..63
                int u    = lin & 15;            // float4 within row of 64
                float4 v = *reinterpret_cast<const float4*>(
                    zb + ((size_t)(c0 + cl) << 14) + u * 4);
                *reinterpret_cast<float4*>(&zs[cl * BN + u * 4]) = v;
            }
            __syncthreads();

            const float* ecol = embT + (size_t)c0 * K_CODES + k0 + 4 * tk;
#pragma unroll 2
            for (int c = 0; c < CB; ++c) {
                float4 z0 = *reinterpret_cast<const float4*>(&zs[c * BN + 8 * tn]);
                float4 z1 = *reinterpret_cast<const float4*>(&zs[c * BN + 8 * tn + 4]);
                const float* ep = ecol + (size_t)c * K_CODES;
                float4 e0 = *reinterpret_cast<const float4*>(ep);        // k-half 0
                float4 e1 = *reinterpret_cast<const float4*>(ep + 128);  // k-half 1
                float zr[8] = {z0.x, z0.y, z0.z, z0.w, z1.x, z1.y, z1.z, z1.w};
                float er[8] = {e0.x, e0.y, e0.z, e0.w, e1.x, e1.y, e1.z, e1.w};
#pragma unroll
                for (int i = 0; i < 8; ++i)
#pragma unroll
                    for (int j = 0; j < 8; ++j)
                        acc[i][j] = fmaf(zr[i], er[j], acc[i][j]);
            }
        }

        // distances + running first-min (per-thread kg strictly ascending:
        // j 0..3 at k0+4tk, then j 4..7 at k0+128+4tk)
#pragma unroll
        for (int j = 0; j < 8; ++j) {
            int kg = k0 + (j < 4 ? 4 * tk + j : 128 + 4 * tk + (j - 4));
#pragma unroll
            for (int i = 0; i < 8; ++i) {
                float t1 = xsl[i] + esql[j];
                float r  = t1 - 2.0f * acc[i][j];
                if (r < minv[i]) { minv[i] = r; mini[i] = kg; }
            }
        }
    }

    // reduce across the 32 tk lanes sharing each tn (32 consecutive lanes)
#pragma unroll
    for (int i = 0; i < 8; ++i) {
        for (int off = 16; off >= 1; off >>= 1) {
            float ov = __shfl_xor(minv[i], off, 64);
            int   oi = __shfl_xor(mini[i], off, 64);
            if (ov < minv[i] || (ov == minv[i] && oi < mini[i])) { minv[i] = ov; mini[i] = oi; }
        }
    }
    if (tk == 0) {
#pragma unroll
        for (int i = 0; i < 8; ++i) {
            int n = n0 + 8 * tn + i;
            out_idx[n] = (float)mini[i];
            atomicAdd(&counts[mini[i]], 1u);
        }
    }
}

// block: fixed b, 1024-s range, 64-c range. idx hoisted per thread (4 s each),
// z/out float4, emb gathered from embT row (4 KB, L1-resident per c).
__global__ __launch_bounds__(256) void gather_kernel(
    const float* __restrict__ z, const float* __restrict__ embT,
    const float* __restrict__ out_idx, float* __restrict__ out,
    double* __restrict__ loss_acc) {
    const int tid = threadIdx.x;
    const int ct = blockIdx.x & 3;          // c-tile (64 c)
    const int st = (blockIdx.x >> 2) & 15;  // s-tile (1024 s)
    const int b  = blockIdx.x >> 6;         // batch
    const int s0 = st * 1024;
    const int c0 = ct * 64;

    int idx[4];
#pragma unroll
    for (int q = 0; q < 4; ++q)
        idx[q] = (int)out_idx[(b << 14) + s0 + 4 * tid + q];

    const float* zb = z + ((size_t)b << 22) + s0 + 4 * tid;
    float* ob = out + ((size_t)b << 22) + s0 + 4 * tid;

    double local = 0.0;
    for (int c = 0; c < 64; ++c) {
        const int cg = c0 + c;
        const float* er = embT + (size_t)cg * K_CODES;
        float4 zv = *reinterpret_cast<const float4*>(zb + ((size_t)cg << 14));
        float4 ov;
        float d0 = er[idx[0]] - zv.x;
        float d1 = er[idx[1]] - zv.y;
        float d2 = er[idx[2]] - zv.z;
        float d3 = er[idx[3]] - zv.w;
        ov.x = zv.x + d0; ov.y = zv.y + d1; ov.z = zv.z + d2; ov.w = zv.w + d3;
        *reinterpret_cast<float4*>(ob + ((size_t)cg << 14)) = ov;
        local += (double)d0 * d0 + (double)d1 * d1 + (double)d2 * d2 + (double)d3 * d3;
    }
    for (int off = 32; off >= 1; off >>= 1) local += __shfl_down(local, off, 64);
    __shared__ double red[4];
    if ((tid & 63) == 0) red[tid >> 6] = local;
    __syncthreads();
    if (tid == 0) {
        double s = red[0] + red[1] + red[2] + red[3];
        atomicAdd(loss_acc, s);
    }
}

__global__ void finalize_kernel(const unsigned* __restrict__ counts,
                                const double* __restrict__ loss_acc,
                                float* __restrict__ out) {
    int tid = threadIdx.x;
    double s = 0.0;
    for (int k = tid; k < K_CODES; k += 256) {
        float avg = (float)counts[k] / 65536.0f;
        float t = avg * logf(avg + 1e-10f);
        s += (double)t;
    }
    for (int off = 32; off >= 1; off >>= 1) s += __shfl_down(s, off, 64);
    __shared__ double red[4];
    if ((tid & 63) == 0) red[tid >> 6] = s;
    __syncthreads();
    if (tid == 0) {
        double tot = red[0] + red[1] + red[2] + red[3];
        out[OUT_PP_OFF]   = expf((float)(-tot));
        out[OUT_LOSS_OFF] = 1.25f * (float)(loss_acc[0] / 16777216.0);
    }
}

extern "C" void kernel_launch(void* const* d_in, const int* in_sizes, int n_in,
                              void* d_out, int out_size, void* d_ws, size_t ws_size,
                              hipStream_t stream) {
    const float* z   = (const float*)d_in[0];
    const float* emb = (const float*)d_in[1];
    float* out = (float*)d_out;

    float*    embT     = (float*)d_ws;
    float*    esq      = (float*)((char*)d_ws + 1048576);
    float*    xsq      = (float*)((char*)d_ws + 1052672);
    unsigned* counts   = (unsigned*)((char*)d_ws + 1314816);
    double*   loss_acc = (double*)((char*)d_ws + 1318912);
    float*    out_idx  = out + OUT_IDX_OFF;

    hipMemsetAsync((char*)d_ws + 1314816, 0, 4104, stream);   // counts + loss
    transpose_kernel<<<dim3(16, 4), 256, 0, stream>>>(emb, embT);
    esq_kernel<<<K_CODES / 64, 256, 0, stream>>>(emb, esq);
    xsq_kernel<<<N_VEC / 256, 256, 0, stream>>>(z, xsq);
    argmin_kernel<<<N_VEC / BN, 256, 0, stream>>>(z, embT, esq, xsq, out_idx, counts);
    gather_kernel<<<256, 256, 0, stream>>>(z, embT, out_idx, out, loss_acc);
    finalize_kernel<<<1, 256, 0, stream>>>(counts, loss_acc, out);
}

// Round 6
// 331.250 us; speedup vs baseline: 2.2232x; 1.7248x over previous
//
#include <hip/hip_runtime.h>

// VQ-VAE vector quantizer, MI355X — MFMA screen + exact-chain refine.
// z: (4,256,16,32,32) f32 ; emb: (1024,256) f32
// out (f32): z_q_st[16777216] | vq_loss | perplexity | indices[65536]
//
// Exactness contract (validated rounds 2-5, absmax 0):
//   x_sq[n], e_sq[k]: numpy pairwise sum of fl32(v*v) (two 128-blocks, 8 accs)
//   xe[n][k]: single sequential f32 FMA chain over c=0..255
//   d = fl32( fl32(x_sq+e_sq) - 2*xe ), argmin first-min tie-break.
//
// Round-6: the chain contract pins full-matrix work to scalar VALU (floor 218us,
// measured 551us). Replace with: bf16-split MFMA screen (zh*eh+zl*eh+zh*el,
// 32x32x16, K=768) tracking (min1,idx,min2) per row; rows with screen gap
// <= T=4e-4 (>= 3x the worst-case |screen-chain| bound of 2*6.6e-5) are
// re-done exactly by the validated scalar chain (refine). Provably identical
// indices; screen error only increases flag rate, never wrongness.
// zh/zl staged in the z_q_st output region (overwritten by gather at the end).

#define C_DIM 256
#define K_CODES 1024
#define N_VEC 65536
#define T_GAP 4e-4f

#define OUT_ZQ_SIZE 16777216
#define OUT_LOSS_OFF 16777216
#define OUT_PP_OFF   16777217
#define OUT_IDX_OFF  16777218

// ws layout (bytes)
#define WS_EH    0          // bf16 [1024][256]            512 KB
#define WS_EL    524288     // bf16 [1024][256]            512 KB
#define WS_ESQ   1048576    // f32 [1024]                    4 KB
#define WS_XSQ   1052672    // f32 [65536]                 256 KB
#define WS_CNT   1314816    // u32 counts[1024]              4 KB
#define WS_LOSS  1318912    // f64 loss                      8 B
#define WS_FLC   1318920    // u32 flag count                4 B
#define WS_SIDX  1318928    // i32 screen_idx[65536]       256 KB
#define WS_FLIST 1581072    // u32 flag_list[65536]        256 KB
#define WS_PM1   1843264    // f32 [4][65536]                1 MB
#define WS_EMBT  1843264    // f32 [256][1024] (overlays PM1; transpose after merge)
#define WS_PM2   2891840    // f32 [4][65536]                1 MB
#define WS_PIX   3940416    // u16 [4][65536]              512 KB  (ends 4464704)

typedef __attribute__((ext_vector_type(8))) short short8;
typedef __attribute__((ext_vector_type(8))) unsigned short ushort8;
typedef __attribute__((ext_vector_type(16))) float f32x16;

__device__ __forceinline__ unsigned short bf16_rne(float v) {
    unsigned u = __float_as_uint(v);
    unsigned r = (u + 0x7FFFu + ((u >> 16) & 1u)) >> 16;
    return (unsigned short)r;
}

// ---------- conversions ----------

__global__ __launch_bounds__(256) void convert_z_kernel(const float* __restrict__ z,
                                                        unsigned short* __restrict__ zh,
                                                        unsigned short* __restrict__ zl) {
    __shared__ float tile[128][65];
    const int tid = threadIdx.x;
    const int n0 = blockIdx.x * 64;
    const int b = n0 >> 14, s0 = n0 & 16383;
    const int ln = tid & 63, cg = tid >> 6;
    const int nl = tid >> 2, q = tid & 3;
    for (int p = 0; p < 2; ++p) {
        __syncthreads();
        for (int i = 0; i < 32; ++i) {
            int c = p * 128 + i * 4 + cg;
            tile[i * 4 + cg][ln] = z[((size_t)b << 22) + ((size_t)c << 14) + s0 + ln];
        }
        __syncthreads();
#pragma unroll
        for (int u = 0; u < 4; ++u) {
            ushort8 hb, lb;
#pragma unroll
            for (int j = 0; j < 8; ++j) {
                float v = tile[q * 32 + u * 8 + j][nl];
                unsigned short h = bf16_rne(v);
                float hf = __uint_as_float((unsigned)h << 16);
                hb[j] = h;
                lb[j] = bf16_rne(v - hf);
            }
            size_t off = (size_t)(n0 + nl) * 256 + p * 128 + q * 32 + u * 8;
            *reinterpret_cast<ushort8*>(zh + off) = hb;
            *reinterpret_cast<ushort8*>(zl + off) = lb;
        }
    }
}

__global__ __launch_bounds__(256) void convert_e_kernel(const float* __restrict__ emb,
                                                        unsigned short* __restrict__ eh,
                                                        unsigned short* __restrict__ el) {
    int i = blockIdx.x * 256 + threadIdx.x;
    float v = emb[i];
    unsigned short h = bf16_rne(v);
    eh[i] = h;
    el[i] = bf16_rne(v - __uint_as_float((unsigned)h << 16));
}

// ---------- exact norms (validated) ----------

__device__ __forceinline__ float pairwise_sq_128(const float* p) {
#pragma clang fp contract(off)
    float r[8];
#pragma unroll
    for (int j = 0; j < 8; ++j) { float v = p[j]; r[j] = v * v; }
#pragma unroll
    for (int i = 8; i < 128; i += 8)
#pragma unroll
        for (int j = 0; j < 8; ++j) { float v = p[i + j]; float t = v * v; r[j] = r[j] + t; }
    return ((r[0] + r[1]) + (r[2] + r[3])) + ((r[4] + r[5]) + (r[6] + r[7]));
}

__global__ __launch_bounds__(256) void esq_kernel(const float* __restrict__ emb,
                                                  float* __restrict__ esq) {
#pragma clang fp contract(off)
    __shared__ float tile[64 * 260];
    const int tid = threadIdx.x;
    const int k0 = blockIdx.x * 64;
#pragma unroll
    for (int r = 0; r < 64; ++r) {
        int idx = r * 256 + tid;
        tile[(idx >> 8) * 260 + (idx & 255)] = emb[k0 * C_DIM + idx];
    }
    __syncthreads();
    if (tid < 64) {
        const float* row = &tile[tid * 260];
        esq[k0 + tid] = pairwise_sq_128(row) + pairwise_sq_128(row + 128);
    }
}

__global__ __launch_bounds__(256) void xsq_kernel(const float* __restrict__ z,
                                                  float* __restrict__ xsq) {
#pragma clang fp contract(off)
    const int n = blockIdx.x * 256 + threadIdx.x;
    const int b = n >> 14, s = n & 16383;
    const float* base = z + ((size_t)b << 22) + s;
    float r[8], res;
#pragma unroll
    for (int j = 0; j < 8; ++j) { float v = base[(size_t)j << 14]; r[j] = v * v; }
#pragma unroll
    for (int i = 8; i < 128; i += 8)
#pragma unroll
        for (int j = 0; j < 8; ++j) { float v = base[(size_t)(i + j) << 14]; float t = v * v; r[j] = r[j] + t; }
    res = ((r[0] + r[1]) + (r[2] + r[3])) + ((r[4] + r[5]) + (r[6] + r[7]));
#pragma unroll
    for (int j = 0; j < 8; ++j) { float v = base[(size_t)(128 + j) << 14]; r[j] = v * v; }
#pragma unroll
    for (int i = 136; i < 256; i += 8)
#pragma unroll
        for (int j = 0; j < 8; ++j) { float v = base[(size_t)(i + j) << 14]; float t = v * v; r[j] = r[j] + t; }
    res = res + (((r[0] + r[1]) + (r[2] + r[3])) + ((r[4] + r[5]) + (r[6] + r[7])));
    xsq[n] = res;
}

__global__ __launch_bounds__(256) void transpose_kernel(const float* __restrict__ emb,
                                                        float* __restrict__ embT) {
    __shared__ float t[64][65];
    const int k0 = blockIdx.x * 64;
    const int c0 = blockIdx.y * 64;
    const int tx = threadIdx.x & 63, ty = threadIdx.x >> 6;
    for (int r = ty; r < 64; r += 4)
        t[r][tx] = emb[(k0 + r) * C_DIM + c0 + tx];
    __syncthreads();
    for (int r = ty; r < 64; r += 4)
        embT[(c0 + r) * K_CODES + k0 + tx] = t[tx][r];
}

// ---------- MFMA screen: 128n x 256k per block, K = 3 x 256 ----------

__global__ __launch_bounds__(256, 2) void screen_kernel(
    const unsigned short* __restrict__ zh, const unsigned short* __restrict__ zl,
    const unsigned short* __restrict__ eh, const unsigned short* __restrict__ el,
    const float* __restrict__ esq, const float* __restrict__ xsq,
    float* __restrict__ pm1, float* __restrict__ pm2,
    unsigned short* __restrict__ pix) {
    __shared__ unsigned short Al[128 * 64];   // swizzled [n-row][64c], 16 KB
    __shared__ unsigned short Bl[256 * 64];   // swizzled [k-row][64c], 32 KB

    const int tid = threadIdx.x;
    const int w = tid >> 6;
    const int l = tid & 63;
    const int lr = l & 31;
    const int lh = l >> 5;
    const int v = (blockIdx.x & 7) * 256 + (blockIdx.x >> 3);   // XCD-chunked swizzle
    const int n0 = (v >> 2) * 128;
    const int kb = v & 3;
    const int k0 = kb * 256;

    f32x16 acc[8];
#pragma unroll
    for (int kt = 0; kt < 8; ++kt)
#pragma unroll
        for (int i = 0; i < 16; ++i) acc[kt][i] = 0.0f;

    for (int seg = 0; seg < 3; ++seg) {
        const unsigned short* As = (seg == 1) ? zl : zh;
        const unsigned short* Bs = (seg == 2) ? el : eh;
        for (int cc = 0; cc < 4; ++cc) {
            const int c0 = cc * 64;
            __syncthreads();
#pragma unroll
            for (int it = 0; it < 4; ++it) {     // A: 1024 x 16B
                int chunk = it * 256 + tid;
                int row = chunk >> 3, c8 = chunk & 7;
                short8 d = *reinterpret_cast<const short8*>(As + (size_t)(n0 + row) * 256 + c0 + c8 * 8);
                *reinterpret_cast<short8*>(&Al[row * 64 + ((c8 ^ (row & 7)) * 8)]) = d;
            }
#pragma unroll
            for (int it = 0; it < 8; ++it) {     // B: 2048 x 16B
                int chunk = it * 256 + tid;
                int row = chunk >> 3, c8 = chunk & 7;
                short8 d = *reinterpret_cast<const short8*>(Bs + (size_t)(k0 + row) * 256 + c0 + c8 * 8);
                *reinterpret_cast<short8*>(&Bl[row * 64 + ((c8 ^ (row & 7)) * 8)]) = d;
            }
            __syncthreads();
#pragma unroll
            for (int ks = 0; ks < 4; ++ks) {
                const int arow = w * 32 + lr;
                const int c8 = ks * 2 + lh;
                short8 af = *reinterpret_cast<const short8*>(&Al[arow * 64 + ((c8 ^ (arow & 7)) * 8)]);
#pragma unroll
                for (int kt = 0; kt < 8; ++kt) {
                    const int brow = kt * 32 + lr;
                    short8 bf = *reinterpret_cast<const short8*>(&Bl[brow * 64 + ((c8 ^ (brow & 7)) * 8)]);
                    acc[kt] = __builtin_amdgcn_mfma_f32_32x32x16_bf16(af, bf, acc[kt], 0, 0, 0);
                }
            }
        }
    }

    // epilogue: per n, (min1, idx1, min2) over this block's 256 k
    float esql[8];
#pragma unroll
    for (int kt = 0; kt < 8; ++kt) esql[kt] = esq[k0 + kt * 32 + lr];

#pragma unroll
    for (int r = 0; r < 16; ++r) {
        const int n = n0 + w * 32 + (r & 3) + 8 * (r >> 2) + 4 * lh;
        const float xs = xsq[n];
        float m1 = 3.4e38f, m2 = 3.4e38f;
        int i1 = 0;
#pragma unroll
        for (int kt = 0; kt < 8; ++kt) {
            float s = (xs + esql[kt]) - 2.0f * acc[kt][r];
            int kg = k0 + kt * 32 + lr;
            if (s < m1) { m2 = m1; m1 = s; i1 = kg; }
            else m2 = fminf(m2, s);
        }
#pragma unroll
        for (int off = 16; off >= 1; off >>= 1) {
            float om1 = __shfl_xor(m1, off, 64);
            float om2 = __shfl_xor(m2, off, 64);
            int   oi1 = __shfl_xor(i1, off, 64);
            if (om1 < m1)      { m2 = fminf(m1, om2); m1 = om1; i1 = oi1; }
            else if (om1 > m1) { m2 = fminf(m2, om1); }
            else               { m2 = m1; i1 = min(i1, oi1); }
        }
        if (lr == 0) {
            size_t p = (size_t)kb * N_VEC + n;
            pm1[p] = m1; pm2[p] = m2; pix[p] = (unsigned short)i1;
        }
    }
}

__global__ __launch_bounds__(256) void merge_kernel(
    const float* __restrict__ pm1, const float* __restrict__ pm2,
    const unsigned short* __restrict__ pix,
    int* __restrict__ screen_idx, unsigned* __restrict__ flag_list,
    unsigned* __restrict__ flag_count) {
    int n = blockIdx.x * 256 + threadIdx.x;
    float m1 = 3.4e38f, m2 = 3.4e38f;
    int i1 = 0;
    for (int kb = 0; kb < 4; ++kb) {
        size_t p = (size_t)kb * N_VEC + n;
        float a1 = pm1[p], a2 = pm2[p];
        int ai = (int)pix[p];
        if (a1 < m1)      { m2 = fminf(m1, a2); m1 = a1; i1 = ai; }
        else if (a1 > m1) { m2 = fminf(m2, a1); }
        else              { m2 = m1; i1 = min(i1, ai); }
    }
    if (m2 - m1 <= T_GAP) {
        screen_idx[n] = -1;
        unsigned pos = atomicAdd(flag_count, 1u);
        flag_list[pos] = (unsigned)n;
    } else {
        screen_idx[n] = i1;
    }
}

// ---------- exact-chain refine of flagged rows (8 rows/group) ----------

__global__ __launch_bounds__(256) void refine_kernel(
    const float* __restrict__ z, const float* __restrict__ embT,
    const float* __restrict__ esq, const float* __restrict__ xsq,
    const unsigned* __restrict__ flag_list, const unsigned* __restrict__ flag_count,
    float* __restrict__ out_idx, unsigned* __restrict__ counts) {
#pragma clang fp contract(off)
    __shared__ float zrow[8][256];
    __shared__ int nrow[8];
    __shared__ unsigned long long red[8][4];
    const int tid = threadIdx.x;
    const unsigned cnt = *flag_count;
    const unsigned groups = (cnt + 7) >> 3;
    const int kbase = tid * 4;
    for (unsigned g = blockIdx.x; g < groups; g += gridDim.x) {
        __syncthreads();
        if (tid < 8) nrow[tid] = (g * 8 + tid < cnt) ? (int)flag_list[g * 8 + tid] : -1;
        __syncthreads();
        for (int r = 0; r < 8; ++r) {
            int n = nrow[r];
            if (n >= 0) {
                int b = n >> 14, s = n & 16383;
                zrow[r][tid] = z[((size_t)b << 22) + ((size_t)tid << 14) + s];
            }
        }
        __syncthreads();
        float acc[8][4];
#pragma unroll
        for (int r = 0; r < 8; ++r)
#pragma unroll
            for (int j = 0; j < 4; ++j) acc[r][j] = 0.0f;
        for (int c4 = 0; c4 < 64; ++c4) {
            float4 ek[4];   // ek[x][j] = e[kbase+j][c4*4+x]
#pragma unroll
            for (int x = 0; x < 4; ++x)
                ek[x] = *reinterpret_cast<const float4*>(embT + (size_t)(c4 * 4 + x) * K_CODES + kbase);
#pragma unroll
            for (int r = 0; r < 8; ++r) {
                float4 zv = *reinterpret_cast<const float4*>(&zrow[r][c4 * 4]);
                {
                    float a;
                    a = acc[r][0];
                    a = fmaf(zv.x, ek[0].x, a); a = fmaf(zv.y, ek[1].x, a);
                    a = fmaf(zv.z, ek[2].x, a); a = fmaf(zv.w, ek[3].x, a);
                    acc[r][0] = a;
                    a = acc[r][1];
                    a = fmaf(zv.x, ek[0].y, a); a = fmaf(zv.y, ek[1].y, a);
                    a = fmaf(zv.z, ek[2].y, a); a = fmaf(zv.w, ek[3].y, a);
                    acc[r][1] = a;
                    a = acc[r][2];
                    a = fmaf(zv.x, ek[0].z, a); a = fmaf(zv.y, ek[1].z, a);
                    a = fmaf(zv.z, ek[2].z, a); a = fmaf(zv.w, ek[3].z, a);
                    acc[r][2] = a;
                    a = acc[r][3];
                    a = fmaf(zv.x, ek[0].w, a); a = fmaf(zv.y, ek[1].w, a);
                    a = fmaf(zv.z, ek[2].w, a); a = fmaf(zv.w, ek[3].w, a);
                    acc[r][3] = a;
                }
            }
        }
        float esql[4];
#pragma unroll
        for (int j = 0; j < 4; ++j) esql[j] = esq[kbase + j];
#pragma unroll
        for (int r = 0; r < 8; ++r) {
            int n = nrow[r];
            float xs = (n >= 0) ? xsq[n] : 0.0f;
            float m = 3.4e38f;
            int mi = 0;
#pragma unroll
            for (int j = 0; j < 4; ++j) {
                float t1 = xs + esql[j];
                float d = t1 - 2.0f * acc[r][j];
                if (d < m) { m = d; mi = kbase + j; }
            }
            unsigned long long p = ((unsigned long long)__float_as_uint(m) << 32) | (unsigned)mi;
            for (int off = 32; off >= 1; off >>= 1) {
                unsigned long long o = __shfl_xor(p, off, 64);
                p = (o < p) ? o : p;
            }
            if ((tid & 63) == 0) red[r][tid >> 6] = p;
        }
        __syncthreads();
        if (tid < 8 && nrow[tid] >= 0) {
            unsigned long long p = red[tid][0];
#pragma unroll
            for (int ww = 1; ww < 4; ++ww) { unsigned long long o = red[tid][ww]; p = (o < p) ? o : p; }
            int idx = (int)(p & 0xFFFFFFFFull);
            out_idx[nrow[tid]] = (float)idx;
            atomicAdd(&counts[idx], 1u);
        }
    }
}

__global__ __launch_bounds__(256) void emit_kernel(const int* __restrict__ screen_idx,
                                                   float* __restrict__ out_idx,
                                                   unsigned* __restrict__ counts) {
    int n = blockIdx.x * 256 + threadIdx.x;
    int iv = screen_idx[n];
    if (iv >= 0) {
        out_idx[n] = (float)iv;
        atomicAdd(&counts[iv], 1u);
    }
}

// ---------- gather + losses (validated) ----------

__global__ __launch_bounds__(256) void gather_kernel(
    const float* __restrict__ z, const float* __restrict__ embT,
    const float* __restrict__ out_idx, float* __restrict__ out,
    double* __restrict__ loss_acc) {
    const int tid = threadIdx.x;
    const int ct = blockIdx.x & 3;
    const int st = (blockIdx.x >> 2) & 15;
    const int b  = blockIdx.x >> 6;
    const int s0 = st * 1024;
    const int c0 = ct * 64;

    int idx[4];
#pragma unroll
    for (int q = 0; q < 4; ++q)
        idx[q] = (int)out_idx[(b << 14) + s0 + 4 * tid + q];

    const float* zb = z + ((size_t)b << 22) + s0 + 4 * tid;
    float* ob = out + ((size_t)b << 22) + s0 + 4 * tid;

    double local = 0.0;
    for (int c = 0; c < 64; ++c) {
        const int cg = c0 + c;
        const float* er = embT + (size_t)cg * K_CODES;
        float4 zv = *reinterpret_cast<const float4*>(zb + ((size_t)cg << 14));
        float4 ov;
        float d0 = er[idx[0]] - zv.x;
        float d1 = er[idx[1]] - zv.y;
        float d2 = er[idx[2]] - zv.z;
        float d3 = er[idx[3]] - zv.w;
        ov.x = zv.x + d0; ov.y = zv.y + d1; ov.z = zv.z + d2; ov.w = zv.w + d3;
        *reinterpret_cast<float4*>(ob + ((size_t)cg << 14)) = ov;
        local += (double)d0 * d0 + (double)d1 * d1 + (double)d2 * d2 + (double)d3 * d3;
    }
    for (int off = 32; off >= 1; off >>= 1) local += __shfl_down(local, off, 64);
    __shared__ double redd[4];
    if ((tid & 63) == 0) redd[tid >> 6] = local;
    __syncthreads();
    if (tid == 0) atomicAdd(loss_acc, redd[0] + redd[1] + redd[2] + redd[3]);
}

__global__ void finalize_kernel(const unsigned* __restrict__ counts,
                                const double* __restrict__ loss_acc,
                                float* __restrict__ out) {
    int tid = threadIdx.x;
    double s = 0.0;
    for (int k = tid; k < K_CODES; k += 256) {
        float avg = (float)counts[k] / 65536.0f;
        float t = avg * logf(avg + 1e-10f);
        s += (double)t;
    }
    for (int off = 32; off >= 1; off >>= 1) s += __shfl_down(s, off, 64);
    __shared__ double red[4];
    if ((tid & 63) == 0) red[tid >> 6] = s;
    __syncthreads();
    if (tid == 0) {
        double tot = red[0] + red[1] + red[2] + red[3];
        out[OUT_PP_OFF]   = expf((float)(-tot));
        out[OUT_LOSS_OFF] = 1.25f * (float)(loss_acc[0] / 16777216.0);
    }
}

extern "C" void kernel_launch(void* const* d_in, const int* in_sizes, int n_in,
                              void* d_out, int out_size, void* d_ws, size_t ws_size,
                              hipStream_t stream) {
    const float* z   = (const float*)d_in[0];
    const float* emb = (const float*)d_in[1];
    float* out = (float*)d_out;
    char* ws = (char*)d_ws;

    unsigned short* eh  = (unsigned short*)(ws + WS_EH);
    unsigned short* el  = (unsigned short*)(ws + WS_EL);
    float*    esq       = (float*)(ws + WS_ESQ);
    float*    xsq       = (float*)(ws + WS_XSQ);
    unsigned* counts    = (unsigned*)(ws + WS_CNT);
    double*   loss_acc  = (double*)(ws + WS_LOSS);
    unsigned* flag_cnt  = (unsigned*)(ws + WS_FLC);
    int*      sidx      = (int*)(ws + WS_SIDX);
    unsigned* flist     = (unsigned*)(ws + WS_FLIST);
    float*    pm1       = (float*)(ws + WS_PM1);
    float*    pm2       = (float*)(ws + WS_PM2);
    unsigned short* pix = (unsigned short*)(ws + WS_PIX);
    float*    embT      = (float*)(ws + WS_EMBT);

    unsigned short* zh = (unsigned short*)out;                      // [0, 33.5 MB)
    unsigned short* zl = (unsigned short*)(out + 8388608);          // [33.5, 67 MB)
    float* out_idx = out + OUT_IDX_OFF;

    hipMemsetAsync(ws + WS_CNT, 0, 4108, stream);   // counts + loss + flag_count

    convert_z_kernel<<<1024, 256, 0, stream>>>(z, zh, zl);
    convert_e_kernel<<<1024, 256, 0, stream>>>(emb, eh, el);
    esq_kernel<<<K_CODES / 64, 256, 0, stream>>>(emb, esq);
    xsq_kernel<<<N_VEC / 256, 256, 0, stream>>>(z, xsq);
    screen_kernel<<<2048, 256, 0, stream>>>(zh, zl, eh, el, esq, xsq, pm1, pm2, pix);
    merge_kernel<<<256, 256, 0, stream>>>(pm1, pm2, pix, sidx, flist, flag_cnt);
    transpose_kernel<<<dim3(16, 4), 256, 0, stream>>>(emb, embT);   // embT overlays pm1
    refine_kernel<<<1024, 256, 0, stream>>>(z, embT, esq, xsq, flist, flag_cnt, out_idx, counts);
    emit_kernel<<<256, 256, 0, stream>>>(sidx, out_idx, counts);
    gather_kernel<<<256, 256, 0, stream>>>(z, embT, out_idx, out, loss_acc);
    finalize_kernel<<<1, 256, 0, stream>>>(counts, loss_acc, out);
}